// Round 4
// baseline (275.133 us; speedup 1.0000x reference)
//
#include <hip/hip_runtime.h>
#include <stdint.h>

typedef unsigned short u16;
typedef __bf16 bf16x8 __attribute__((ext_vector_type(8)));
typedef float f32x4 __attribute__((ext_vector_type(4)));
typedef float f32x16 __attribute__((ext_vector_type(16)));
typedef unsigned short u16x8 __attribute__((ext_vector_type(8)));
typedef unsigned short u16x4 __attribute__((ext_vector_type(4)));

#define HD 16
#define BB 4
#define SS 2048
#define DD 1024
#define DH 64

#if __has_builtin(__builtin_amdgcn_exp2f)
#define EXP2(x) __builtin_amdgcn_exp2f(x)
#else
#define EXP2(x) exp2f(x)
#endif

__device__ __forceinline__ u16 f2bf(float f) {
  union { float f; uint32_t u; } v; v.f = f;
  uint32_t u = v.u;
  return (u16)((u + 0x7FFFu + ((u >> 16) & 1u)) >> 16);  // RNE, no NaN in data
}

// native converter for hot paths (single v_cvt, RNE)
__device__ __forceinline__ u16 bfbits(float f) {
  union { __bf16 h; u16 u; } c;
  c.h = (__bf16)f;
  return c.u;
}

// pack two f32 -> u32 of 2 bf16 (lo = first arg), single instruction.
__device__ __forceinline__ uint32_t cvtpk(float lo, float hi) {
  uint32_t r;
  asm("v_cvt_pk_bf16_f32 %0, %1, %2" : "=v"(r) : "v"(lo), "v"(hi));
  return r;
}

__device__ __forceinline__ void gl2lds16(const void* g, void* l) {
  __builtin_amdgcn_global_load_lds(
      (const __attribute__((address_space(1))) void*)g,
      (__attribute__((address_space(3))) void*)l, 16, 0, 0);
}

// ---------------- cast x (fp32 -> bf16), 4 elems/thread ----------------
__global__ __launch_bounds__(256) void cast_x_kernel(const float* __restrict__ src,
                                                     u16* __restrict__ dst, int n4) {
  int i = blockIdx.x * 256 + threadIdx.x;
  if (i >= n4) return;
  float4 v = ((const float4*)src)[i];
  u16x4 o;
  o.x = f2bf(v.x); o.y = f2bf(v.y); o.z = f2bf(v.z); o.w = f2bf(v.w);
  ((u16x4*)dst)[i] = o;
}

// ------ transpose + cast all 4 weights in one launch: blockIdx.z picks the weight ------
__global__ __launch_bounds__(256) void wtrans4_kernel(const float* __restrict__ WQ,
                                                      const float* __restrict__ WK,
                                                      const float* __restrict__ WV,
                                                      const float* __restrict__ WO,
                                                      u16* __restrict__ wcat,
                                                      u16* __restrict__ wot, float qscale) {
  __shared__ u16 tile[64][65];
  const int z = blockIdx.z;
  const float* src = (z == 0) ? WQ : (z == 1) ? WK : (z == 2) ? WV : WO;
  u16* dst = (z < 3) ? wcat + (size_t)z * 1024 * 1024 : wot;
  const float scale = (z == 0) ? qscale : 1.0f;
  const int bx = blockIdx.x * 64;  // src col (n)
  const int by = blockIdx.y * 64;  // src row (k)
  const int t = threadIdx.x;
  const int c = t & 63, r0 = t >> 6;
#pragma unroll
  for (int r = r0; r < 64; r += 4)
    tile[r][c] = f2bf(src[(size_t)(by + r) * 1024 + bx + c] * scale);
  __syncthreads();
#pragma unroll
  for (int r = r0; r < 64; r += 4)
    dst[(size_t)(bx + r) * 1024 + by + c] = tile[c][r];
}

// ------------- V transpose: qkv[b*S+s][2048 + h*64 + d] -> vt[((b*16+h)*64+d)][s] -------------
__global__ __launch_bounds__(256) void vtrans_kernel(const u16* __restrict__ qkv,
                                                     u16* __restrict__ vt) {
  __shared__ u16 tile[64][65];
  const int s0 = blockIdx.x * 64;
  const int h = blockIdx.y;
  const int b = blockIdx.z;
  const int t = threadIdx.x;
  const int c = t & 63, r0 = t >> 6;
#pragma unroll
  for (int r = r0; r < 64; r += 4)
    tile[r][c] = qkv[(size_t)(b * SS + s0 + r) * 3072 + 2048 + h * DH + c];
  __syncthreads();
#pragma unroll
  for (int r = r0; r < 64; r += 4)
    vt[((size_t)(b * HD + h) * DH + r) * SS + s0 + c] = tile[c][r];
}

// ---------------- NT GEMM, BK=64, 128x128 tile, 32x32x16 MFMA ----------------
// (unchanged this round — attn is the target for clean attribution)
template <int OUT_BF16>
__global__ __launch_bounds__(256) void gemm_nt_kernel(const u16* __restrict__ A,
                                                      const u16* __restrict__ Bt,
                                                      void* __restrict__ Cv,
                                                      int M, int N, int K) {
  __shared__ __attribute__((aligned(16))) u16 As[128 * 64];  // 16 KB
  __shared__ __attribute__((aligned(16))) u16 Bs[128 * 64];  // 16 KB
  const int t = threadIdx.x;
  const int lane = t & 63;
  const int w = t >> 6;
  const int m0 = blockIdx.y * 128;
  const int n0 = blockIdx.x * 128;

  f32x16 acc[2][2] = {};

  const int srow = t >> 3;            // staging row within pass (0..31)
  const int cpos = t & 7;             // chunk slot 0..7
  const int scc = cpos ^ (srow & 7);  // XOR-swizzled chunk (pass-invariant)
  const int wm = (w >> 1) * 64;
  const int wn = (w & 1) * 64;
  const int l31 = lane & 31;
  const int kh = lane >> 5;  // 0/1: which 8-wide k-half of the 16-wide instr K

  for (int k0 = 0; k0 < K; k0 += 64) {
#pragma unroll
    for (int p = 0; p < 4; ++p) {
      int row = p * 32 + srow;
      gl2lds16(A + (size_t)(m0 + row) * K + k0 + scc * 8, (char*)As + p * 4096 + w * 1024);
      gl2lds16(Bt + (size_t)(n0 + row) * K + k0 + scc * 8, (char*)Bs + p * 4096 + w * 1024);
    }
    __syncthreads();

#pragma unroll
    for (int ks = 0; ks < 4; ++ks) {  // 4 x K=16
      bf16x8 af[2], bfr[2];
#pragma unroll
      for (int i = 0; i < 2; ++i) {
        int ra = wm + i * 32 + l31;
        af[i] = *(const bf16x8*)(As + ra * 64 + (((ks * 2 + kh) ^ (ra & 7)) * 8));
        int rb = wn + i * 32 + l31;
        bfr[i] = *(const bf16x8*)(Bs + rb * 64 + (((ks * 2 + kh) ^ (rb & 7)) * 8));
      }
#pragma unroll
      for (int i = 0; i < 2; ++i)
#pragma unroll
        for (int j = 0; j < 2; ++j)
          acc[i][j] = __builtin_amdgcn_mfma_f32_32x32x16_bf16(af[i], bfr[j], acc[i][j], 0, 0, 0);
    }
    __syncthreads();
  }

#pragma unroll
  for (int i = 0; i < 2; ++i)
#pragma unroll
    for (int j = 0; j < 2; ++j)
#pragma unroll
      for (int rg = 0; rg < 16; ++rg) {
        int gr = m0 + wm + i * 32 + (rg & 3) + ((rg >> 2) * 8) + 4 * kh;
        int gc = n0 + wn + j * 32 + l31;
        float v = acc[i][j][rg];
        if (OUT_BF16)
          ((u16*)Cv)[(size_t)gr * N + gc] = f2bf(v);
        else
          ((float*)Cv)[(size_t)gr * N + gc] = v;
      }
}

// ---------------- flash attention: per (qtile128, h, b) ----------------
// R14: R13's 32x32 structure kept, bank-swizzle fixed. R13's conflicts were
// EXACTLY 2^23 extra = 4 cyc per ds_read_b128: its chunk = ksk ^ (r&7) gives
// lanes 0..7 (l3=0 in the p31 A-row map) only 4 distinct bank-quadruples, and
// consecutive tt/dt reads had identical phase maps. New swizzle:
//   sigma(r) = (r&3) | (((r>>2)^(r>>3)^(r>>5))&1)<<2
// Octet-injective for BOTH patterns (K-octets: row-bit3 free, bit2 fixed;
// V-octets: bit2 free, bit3 fixed; bit2^bit3 varies in both) and the r>>5
// term (=tt/dt) de-correlates consecutive instructions. Staging: linear LDS
// dest + sigma-preswizzled global chunk (both-sides rule). All else = R13.
__global__ __launch_bounds__(256, 4) void attn_kernel(const u16* __restrict__ qkv,
                                                      const u16* __restrict__ vt,
                                                      u16* __restrict__ ctx) {
  __shared__ __attribute__((aligned(16))) u16 SMEM[9216];  // 18.4 KB (Ks|Vs, reused as Es)
  u16* Ks = SMEM;          // [64 key][64 d], chunk slot = g ^ sigma(row)
  u16* Vs = SMEM + 4096;   // [64 d][64 key], chunk slot = g ^ sigma(row)

  const int t = threadIdx.x;
  const int lane = t & 63;
  const int w = t >> 6;
  const int q0 = blockIdx.x * 128;
  const int h = blockIdx.y;
  const int b = blockIdx.z;

  const int srow = t >> 3;  // staging row (0..31 per pass)
  const int cpos = t & 7;
  const size_t qkv_row0 = (size_t)(b * SS) * 3072;
  const size_t vtbase = ((size_t)(b * HD + h) * DH) * SS;

  const int l31 = lane & 31;
  const int kh = lane >> 5;
  // pi: swap bits 2<->3 (C-row rho -> key), so regs line up as PV B-frags
  const int p31 = (l31 & 19) | ((l31 & 4) << 1) | ((l31 & 8) >> 1);
  // per-lane sigma bases (tt/dt add ^4 via the r>>5 term)
  const int sK0 = (p31 & 3) | ((((p31 >> 2) ^ (p31 >> 3)) & 1) << 2);
  const int sV0 = (l31 & 3) | ((((l31 >> 2) ^ (l31 >> 3)) & 1) << 2);

  // Q frags (loaded once): q = q0 + w*32 + l31, d = ks*16 + kh*8 + {0..7}.
  // WQ carries 1/sqrt(D)*log2(e).
  bf16x8 aq[4];
#pragma unroll
  for (int ks = 0; ks < 4; ++ks)
    aq[ks] = *(const bf16x8*)(qkv + qkv_row0 + (size_t)(q0 + w * 32 + l31) * 3072 +
                              h * DH + ks * 16 + kh * 8);

  f32x16 ot[2] = {};  // O^T: ot[dt][r] -> d = dt*32+(r&3)+8*(r>>2)+4*kh, q = l31
  float l_p = 0.f;    // per-lane partial sum of 2^s (lane's 32 keys per iter)

  for (int k0 = 0; k0 < SS; k0 += 64) {
    // stage K tile ([64 key][64 d]) and V^T tile ([64 d][64 key])
#pragma unroll
    for (int p = 0; p < 2; ++p) {
      int r = p * 32 + srow;
      int sg = (r & 3) | ((((r >> 2) ^ (r >> 3) ^ (r >> 5)) & 1) << 2);
      int cc = cpos ^ sg;
      gl2lds16(qkv + qkv_row0 + (size_t)(k0 + r) * 3072 + 1024 + h * DH + cc * 8,
               (char*)Ks + p * 4096 + w * 1024);
      gl2lds16(vt + vtbase + (size_t)r * SS + k0 + cc * 8,
               (char*)Vs + p * 4096 + w * 1024);
    }
    __syncthreads();

    // S^T = K Q^T: c2[t][r] = P[key = t*32+16*(r>>3)+8*kh+4*((r>>2)&1)+(r&3)][q=l31]
    f32x16 c2[2] = {};
#pragma unroll
    for (int ks = 0; ks < 4; ++ks) {
#pragma unroll
      for (int tt = 0; tt < 2; ++tt) {
        int jr = tt * 32 + p31;
        int slot = (ks * 2 + kh) ^ sK0 ^ (tt << 2);
        bf16x8 ak = *(const bf16x8*)(Ks + jr * 64 + slot * 8);
        c2[tt] = __builtin_amdgcn_mfma_f32_32x32x16_bf16(ak, aq[ks], c2[tt], 0, 0, 0);
      }
    }

    // P = 2^s in place; per-lane partial l
#pragma unroll
    for (int tt = 0; tt < 2; ++tt)
#pragma unroll
      for (int r = 0; r < 16; ++r)
        c2[tt][r] = EXP2(c2[tt][r]);
    {
      float s0 = 0.f, s1 = 0.f;
#pragma unroll
      for (int r = 0; r < 16; ++r) { s0 += c2[0][r]; s1 += c2[1][r]; }
      l_p += s0 + s1;
    }

    // pack P^T B-frags fully in-register: bp[2t+hf].elem[j] = c2[t][8*hf+j]
    union { uint32_t u[4]; bf16x8 b; } bp[4];
#pragma unroll
    for (int tt = 0; tt < 2; ++tt)
#pragma unroll
      for (int hf = 0; hf < 2; ++hf)
#pragma unroll
        for (int i = 0; i < 4; ++i)
          bp[tt * 2 + hf].u[i] =
              cvtpk(c2[tt][hf * 8 + 2 * i], c2[tt][hf * 8 + 2 * i + 1]);

    // O^T += V^T P^T  (A = V^T rows = d, straight from Vs)
#pragma unroll
    for (int ks = 0; ks < 4; ++ks) {
#pragma unroll
      for (int dt = 0; dt < 2; ++dt) {
        int vr = dt * 32 + l31;
        int slot = (ks * 2 + kh) ^ sV0 ^ (dt << 2);
        bf16x8 av = *(const bf16x8*)(Vs + vr * 64 + slot * 8);
        ot[dt] = __builtin_amdgcn_mfma_f32_32x32x16_bf16(av, bp[ks].b, ot[dt], 0, 0, 0);
      }
    }
    __syncthreads();  // protect Ks/Vs before next staging
  }

  // epilogue: l across the two kh halves (lanes l, l+32 share q = l31)
  l_p += __shfl_xor(l_p, 32, 64);
  const float inv_l = 1.0f / l_p;

  // normalize + stage O^T -> Es[128 q][72] (reused SMEM; wave-local rows)
  u16* Es = SMEM;
#pragma unroll
  for (int dt = 0; dt < 2; ++dt)
#pragma unroll
    for (int rq = 0; rq < 4; ++rq) {
      u16x4 pv;
#pragma unroll
      for (int i = 0; i < 4; ++i) pv[i] = bfbits(ot[dt][rq * 4 + i] * inv_l);
      *(u16x4*)(Es + (w * 32 + l31) * 72 + dt * 32 + rq * 8 + kh * 4) = pv;
    }

  const int rr = lane >> 3;  // 0..7
  const int cc8 = lane & 7;  // 16B chunk
#pragma unroll
  for (int p = 0; p < 4; ++p) {
    int row = w * 32 + p * 8 + rr;
    u16x8 vv = *(const u16x8*)(Es + row * 72 + cc8 * 8);
    *(u16x8*)(ctx + (size_t)(b * SS + q0 + row) * DD + h * DH + cc8 * 8) = vv;
  }
}

extern "C" void kernel_launch(void* const* d_in, const int* in_sizes, int n_in,
                              void* d_out, int out_size, void* d_ws, size_t ws_size,
                              hipStream_t stream) {
  (void)in_sizes; (void)n_in; (void)out_size; (void)ws_size;
  const float* x = (const float*)d_in[0];
  const float* WQ = (const float*)d_in[1];
  const float* WK = (const float*)d_in[2];
  const float* WV = (const float*)d_in[3];
  const float* WO = (const float*)d_in[4];

  char* ws = (char*)d_ws;
  u16* xb = (u16*)ws;            ws += (size_t)8192 * 1024 * 2;   // 16.8 MB (reused as ctx)
  u16* wcat = (u16*)ws;          ws += (size_t)3072 * 1024 * 2;   // 6.3 MB
  u16* wot = (u16*)ws;           ws += (size_t)1024 * 1024 * 2;   // 2.1 MB
  u16* qkv = (u16*)ws;           ws += (size_t)8192 * 3072 * 2;   // 50.3 MB
  u16* vt = (u16*)ws;            ws += (size_t)BB * HD * DH * SS * 2;  // 16.8 MB
  u16* ctx = xb;  // x consumed by QKV GEMM before attention writes ctx

  // 1/sqrt(1024) * log2(e): softmax runs in exp2 domain with scale folded into WQ
  const float QSCALE = 0.03125f * 1.4426950408889634f;

  cast_x_kernel<<<dim3(8192), dim3(256), 0, stream>>>(x, xb, 2097152);
  wtrans4_kernel<<<dim3(16, 16, 4), dim3(256), 0, stream>>>(WQ, WK, WV, WO, wcat, wot, QSCALE);

  gemm_nt_kernel<1><<<dim3(24, 64), dim3(256), 0, stream>>>(xb, wcat, (void*)qkv, 8192, 3072, 1024);
  vtrans_kernel<<<dim3(32, 16, 4), dim3(256), 0, stream>>>(qkv, vt);
  attn_kernel<<<dim3(16, 16, 4), dim3(256), 0, stream>>>(qkv, vt, ctx);
  gemm_nt_kernel<0><<<dim3(8, 64), dim3(256), 0, stream>>>(ctx, wot, d_out, 8192, 1024, 1024);
}

// Round 5
// 257.674 us; speedup vs baseline: 1.0678x; 1.0678x over previous
//
#include <hip/hip_runtime.h>
#include <stdint.h>

typedef unsigned short u16;
typedef __bf16 bf16x8 __attribute__((ext_vector_type(8)));
typedef float f32x4 __attribute__((ext_vector_type(4)));
typedef float f32x16 __attribute__((ext_vector_type(16)));
typedef unsigned short u16x8 __attribute__((ext_vector_type(8)));
typedef unsigned short u16x4 __attribute__((ext_vector_type(4)));

#define HD 16
#define BB 4
#define SS 2048
#define DD 1024
#define DH 64

#if __has_builtin(__builtin_amdgcn_exp2f)
#define EXP2(x) __builtin_amdgcn_exp2f(x)
#else
#define EXP2(x) exp2f(x)
#endif

__device__ __forceinline__ u16 f2bf(float f) {
  union { float f; uint32_t u; } v; v.f = f;
  uint32_t u = v.u;
  return (u16)((u + 0x7FFFu + ((u >> 16) & 1u)) >> 16);  // RNE, no NaN in data
}

// native converter for hot paths (single v_cvt, RNE)
__device__ __forceinline__ u16 bfbits(float f) {
  union { __bf16 h; u16 u; } c;
  c.h = (__bf16)f;
  return c.u;
}

// pack two f32 -> u32 of 2 bf16 (lo = first arg), single instruction.
__device__ __forceinline__ uint32_t cvtpk(float lo, float hi) {
  uint32_t r;
  asm("v_cvt_pk_bf16_f32 %0, %1, %2" : "=v"(r) : "v"(lo), "v"(hi));
  return r;
}

__device__ __forceinline__ void gl2lds16(const void* g, void* l) {
  __builtin_amdgcn_global_load_lds(
      (const __attribute__((address_space(1))) void*)g,
      (__attribute__((address_space(3))) void*)l, 16, 0, 0);
}

// ---------------- cast x (fp32 -> bf16), 4 elems/thread ----------------
__global__ __launch_bounds__(256) void cast_x_kernel(const float* __restrict__ src,
                                                     u16* __restrict__ dst, int n4) {
  int i = blockIdx.x * 256 + threadIdx.x;
  if (i >= n4) return;
  float4 v = ((const float4*)src)[i];
  u16x4 o;
  o.x = f2bf(v.x); o.y = f2bf(v.y); o.z = f2bf(v.z); o.w = f2bf(v.w);
  ((u16x4*)dst)[i] = o;
}

// ------ transpose + cast all 4 weights in one launch: blockIdx.z picks the weight ------
__global__ __launch_bounds__(256) void wtrans4_kernel(const float* __restrict__ WQ,
                                                      const float* __restrict__ WK,
                                                      const float* __restrict__ WV,
                                                      const float* __restrict__ WO,
                                                      u16* __restrict__ wcat,
                                                      u16* __restrict__ wot, float qscale) {
  __shared__ u16 tile[64][65];
  const int z = blockIdx.z;
  const float* src = (z == 0) ? WQ : (z == 1) ? WK : (z == 2) ? WV : WO;
  u16* dst = (z < 3) ? wcat + (size_t)z * 1024 * 1024 : wot;
  const float scale = (z == 0) ? qscale : 1.0f;
  const int bx = blockIdx.x * 64;  // src col (n)
  const int by = blockIdx.y * 64;  // src row (k)
  const int t = threadIdx.x;
  const int c = t & 63, r0 = t >> 6;
#pragma unroll
  for (int r = r0; r < 64; r += 4)
    tile[r][c] = f2bf(src[(size_t)(by + r) * 1024 + bx + c] * scale);
  __syncthreads();
#pragma unroll
  for (int r = r0; r < 64; r += 4)
    dst[(size_t)(bx + r) * 1024 + by + c] = tile[c][r];
}

// ------------- V transpose: qkv[b*S+s][2048 + h*64 + d] -> vt[((b*16+h)*64+d)][s] -------------
__global__ __launch_bounds__(256) void vtrans_kernel(const u16* __restrict__ qkv,
                                                     u16* __restrict__ vt) {
  __shared__ u16 tile[64][65];
  const int s0 = blockIdx.x * 64;
  const int h = blockIdx.y;
  const int b = blockIdx.z;
  const int t = threadIdx.x;
  const int c = t & 63, r0 = t >> 6;
#pragma unroll
  for (int r = r0; r < 64; r += 4)
    tile[r][c] = qkv[(size_t)(b * SS + s0 + r) * 3072 + 2048 + h * DH + c];
  __syncthreads();
#pragma unroll
  for (int r = r0; r < 64; r += 4)
    vt[((size_t)(b * HD + h) * DH + r) * SS + s0 + c] = tile[c][r];
}

// ---------------- NT GEMM, BK=64, 128x128 tile, 32x32x16 MFMA ----------------
// (unchanged this round — attn is the target for clean attribution)
template <int OUT_BF16>
__global__ __launch_bounds__(256) void gemm_nt_kernel(const u16* __restrict__ A,
                                                      const u16* __restrict__ Bt,
                                                      void* __restrict__ Cv,
                                                      int M, int N, int K) {
  __shared__ __attribute__((aligned(16))) u16 As[128 * 64];  // 16 KB
  __shared__ __attribute__((aligned(16))) u16 Bs[128 * 64];  // 16 KB
  const int t = threadIdx.x;
  const int lane = t & 63;
  const int w = t >> 6;
  const int m0 = blockIdx.y * 128;
  const int n0 = blockIdx.x * 128;

  f32x16 acc[2][2] = {};

  const int srow = t >> 3;            // staging row within pass (0..31)
  const int cpos = t & 7;             // chunk slot 0..7
  const int scc = cpos ^ (srow & 7);  // XOR-swizzled chunk (pass-invariant)
  const int wm = (w >> 1) * 64;
  const int wn = (w & 1) * 64;
  const int l31 = lane & 31;
  const int kh = lane >> 5;  // 0/1: which 8-wide k-half of the 16-wide instr K

  for (int k0 = 0; k0 < K; k0 += 64) {
#pragma unroll
    for (int p = 0; p < 4; ++p) {
      int row = p * 32 + srow;
      gl2lds16(A + (size_t)(m0 + row) * K + k0 + scc * 8, (char*)As + p * 4096 + w * 1024);
      gl2lds16(Bt + (size_t)(n0 + row) * K + k0 + scc * 8, (char*)Bs + p * 4096 + w * 1024);
    }
    __syncthreads();

#pragma unroll
    for (int ks = 0; ks < 4; ++ks) {  // 4 x K=16
      bf16x8 af[2], bfr[2];
#pragma unroll
      for (int i = 0; i < 2; ++i) {
        int ra = wm + i * 32 + l31;
        af[i] = *(const bf16x8*)(As + ra * 64 + (((ks * 2 + kh) ^ (ra & 7)) * 8));
        int rb = wn + i * 32 + l31;
        bfr[i] = *(const bf16x8*)(Bs + rb * 64 + (((ks * 2 + kh) ^ (rb & 7)) * 8));
      }
#pragma unroll
      for (int i = 0; i < 2; ++i)
#pragma unroll
        for (int j = 0; j < 2; ++j)
          acc[i][j] = __builtin_amdgcn_mfma_f32_32x32x16_bf16(af[i], bfr[j], acc[i][j], 0, 0, 0);
    }
    __syncthreads();
  }

#pragma unroll
  for (int i = 0; i < 2; ++i)
#pragma unroll
    for (int j = 0; j < 2; ++j)
#pragma unroll
      for (int rg = 0; rg < 16; ++rg) {
        int gr = m0 + wm + i * 32 + (rg & 3) + ((rg >> 2) * 8) + 4 * kh;
        int gc = n0 + wn + j * 32 + l31;
        float v = acc[i][j][rg];
        if (OUT_BF16)
          ((u16*)Cv)[(size_t)gr * N + gc] = f2bf(v);
        else
          ((float*)Cv)[(size_t)gr * N + gc] = v;
      }
}

// ---------------- flash attention: per (qtile256, h, b) ----------------
// R15: q-per-wave doubled to 64 (QBLK=256, grid 512 = 2 blocks/CU). Each
// K-frag / V-frag ds_read_b128 now feeds TWO MFMA (qq=0,1): LDS reads per
// unit work halve (per-CU LDS-read cyc ~98K -> ~49K), making MFMA the top
// pipe (~65K cyc) for the first time. R14 lesson: the 4-cyc/read conflict
// residue is swizzle-invariant (8,585,216 across two schemes) — pattern-
// intrinsic, not fixable from source; sigma swizzle kept as-is.
// Regs: ot 4xf32x16 + c2 4xf32x16 + aq 8 + bp 8 ~ 185 peak -> bounds(256,2).
// Es epilogue needs [256 q][72] = 36.9 KB; SMEM sized for it (Ks/Vs reuse).
__global__ __launch_bounds__(256, 2) void attn_kernel(const u16* __restrict__ qkv,
                                                      const u16* __restrict__ vt,
                                                      u16* __restrict__ ctx) {
  __shared__ __attribute__((aligned(16))) u16 SMEM[18432];  // 36.9 KB (Ks|Vs, reused as Es)
  u16* Ks = SMEM;          // [64 key][64 d], chunk slot = g ^ sigma(row)
  u16* Vs = SMEM + 4096;   // [64 d][64 key], chunk slot = g ^ sigma(row)

  const int t = threadIdx.x;
  const int lane = t & 63;
  const int w = t >> 6;
  const int q0 = blockIdx.x * 256;
  const int h = blockIdx.y;
  const int b = blockIdx.z;

  const int srow = t >> 3;  // staging row (0..31 per pass)
  const int cpos = t & 7;
  const size_t qkv_row0 = (size_t)(b * SS) * 3072;
  const size_t vtbase = ((size_t)(b * HD + h) * DH) * SS;

  const int l31 = lane & 31;
  const int kh = lane >> 5;
  // pi: swap bits 2<->3 (C-row rho -> key), so regs line up as PV B-frags
  const int p31 = (l31 & 19) | ((l31 & 4) << 1) | ((l31 & 8) >> 1);
  // per-lane sigma bases (tt/dt add ^4 via the r>>5 term)
  const int sK0 = (p31 & 3) | ((((p31 >> 2) ^ (p31 >> 3)) & 1) << 2);
  const int sV0 = (l31 & 3) | ((((l31 >> 2) ^ (l31 >> 3)) & 1) << 2);

  // Q frags (loaded once): q = q0 + w*64 + qq*32 + l31, d = ks*16 + kh*8 + {0..7}.
  // WQ carries 1/sqrt(D)*log2(e).
  bf16x8 aq[2][4];
#pragma unroll
  for (int qq = 0; qq < 2; ++qq)
#pragma unroll
    for (int ks = 0; ks < 4; ++ks)
      aq[qq][ks] = *(const bf16x8*)(qkv + qkv_row0 +
                                    (size_t)(q0 + w * 64 + qq * 32 + l31) * 3072 +
                                    h * DH + ks * 16 + kh * 8);

  f32x16 ot[2][2] = {};       // ot[qq][dt][r]: d = dt*32+(r&3)+8*(r>>2)+4*kh, q = qq half
  float l_p0 = 0.f, l_p1 = 0.f;  // per-lane partial sum of 2^s, per qq

  for (int k0 = 0; k0 < SS; k0 += 64) {
    // stage K tile ([64 key][64 d]) and V^T tile ([64 d][64 key])
#pragma unroll
    for (int p = 0; p < 2; ++p) {
      int r = p * 32 + srow;
      int sg = (r & 3) | ((((r >> 2) ^ (r >> 3) ^ (r >> 5)) & 1) << 2);
      int cc = cpos ^ sg;
      gl2lds16(qkv + qkv_row0 + (size_t)(k0 + r) * 3072 + 1024 + h * DH + cc * 8,
               (char*)Ks + p * 4096 + w * 1024);
      gl2lds16(vt + vtbase + (size_t)r * SS + k0 + cc * 8,
               (char*)Vs + p * 4096 + w * 1024);
    }
    __syncthreads();

    // S^T = K Q^T: c2[qq][t][r] = P[key = t*32+16*(r>>3)+8*kh+4*((r>>2)&1)+(r&3)][q]
    // One ak read feeds both qq MFMA (the 2x reuse this round buys).
    f32x16 c2[2][2] = {};
#pragma unroll
    for (int ks = 0; ks < 4; ++ks) {
#pragma unroll
      for (int tt = 0; tt < 2; ++tt) {
        int jr = tt * 32 + p31;
        int slot = (ks * 2 + kh) ^ sK0 ^ (tt << 2);
        bf16x8 ak = *(const bf16x8*)(Ks + jr * 64 + slot * 8);
        c2[0][tt] = __builtin_amdgcn_mfma_f32_32x32x16_bf16(ak, aq[0][ks], c2[0][tt], 0, 0, 0);
        c2[1][tt] = __builtin_amdgcn_mfma_f32_32x32x16_bf16(ak, aq[1][ks], c2[1][tt], 0, 0, 0);
      }
    }

    // P = 2^s in place; per-lane partial l per qq
#pragma unroll
    for (int qq = 0; qq < 2; ++qq)
#pragma unroll
      for (int tt = 0; tt < 2; ++tt)
#pragma unroll
        for (int r = 0; r < 16; ++r)
          c2[qq][tt][r] = EXP2(c2[qq][tt][r]);
    {
      float s0 = 0.f, s1 = 0.f;
#pragma unroll
      for (int r = 0; r < 16; ++r) { s0 += c2[0][0][r]; s0 += c2[0][1][r]; }
#pragma unroll
      for (int r = 0; r < 16; ++r) { s1 += c2[1][0][r]; s1 += c2[1][1][r]; }
      l_p0 += s0; l_p1 += s1;
    }

    // pack P^T B-frags fully in-register: bp[qq][2t+hf].elem[j] = c2[qq][t][8*hf+j]
    union { uint32_t u[4]; bf16x8 b; } bp[2][4];
#pragma unroll
    for (int qq = 0; qq < 2; ++qq)
#pragma unroll
      for (int tt = 0; tt < 2; ++tt)
#pragma unroll
        for (int hf = 0; hf < 2; ++hf)
#pragma unroll
          for (int i = 0; i < 4; ++i)
            bp[qq][tt * 2 + hf].u[i] =
                cvtpk(c2[qq][tt][hf * 8 + 2 * i], c2[qq][tt][hf * 8 + 2 * i + 1]);

    // O^T += V^T P^T  (A = V^T rows = d; one av read feeds both qq MFMA)
#pragma unroll
    for (int ks = 0; ks < 4; ++ks) {
#pragma unroll
      for (int dt = 0; dt < 2; ++dt) {
        int vr = dt * 32 + l31;
        int slot = (ks * 2 + kh) ^ sV0 ^ (dt << 2);
        bf16x8 av = *(const bf16x8*)(Vs + vr * 64 + slot * 8);
        ot[0][dt] = __builtin_amdgcn_mfma_f32_32x32x16_bf16(av, bp[0][ks].b, ot[0][dt], 0, 0, 0);
        ot[1][dt] = __builtin_amdgcn_mfma_f32_32x32x16_bf16(av, bp[1][ks].b, ot[1][dt], 0, 0, 0);
      }
    }
    __syncthreads();  // protect Ks/Vs before next staging
  }

  // epilogue: l across the two kh halves (lanes l, l+32 share q)
  l_p0 += __shfl_xor(l_p0, 32, 64);
  l_p1 += __shfl_xor(l_p1, 32, 64);
  const float inv_l0 = 1.0f / l_p0;
  const float inv_l1 = 1.0f / l_p1;

  // normalize + stage O^T -> Es[256 q][72] (reused SMEM; wave-local rows)
  u16* Es = SMEM;
#pragma unroll
  for (int qq = 0; qq < 2; ++qq) {
    const float il = qq ? inv_l1 : inv_l0;
#pragma unroll
    for (int dt = 0; dt < 2; ++dt)
#pragma unroll
      for (int rq = 0; rq < 4; ++rq) {
        u16x4 pv;
#pragma unroll
        for (int i = 0; i < 4; ++i) pv[i] = bfbits(ot[qq][dt][rq * 4 + i] * il);
        *(u16x4*)(Es + (w * 64 + qq * 32 + l31) * 72 + dt * 32 + rq * 8 + kh * 4) = pv;
      }
  }

  const int rr = lane >> 3;  // 0..7
  const int cc8 = lane & 7;  // 16B chunk
#pragma unroll
  for (int p = 0; p < 8; ++p) {
    int row = w * 64 + p * 8 + rr;
    u16x8 vv = *(const u16x8*)(Es + row * 72 + cc8 * 8);
    *(u16x8*)(ctx + (size_t)(b * SS + q0 + row) * DD + h * DH + cc8 * 8) = vv;
  }
}

extern "C" void kernel_launch(void* const* d_in, const int* in_sizes, int n_in,
                              void* d_out, int out_size, void* d_ws, size_t ws_size,
                              hipStream_t stream) {
  (void)in_sizes; (void)n_in; (void)out_size; (void)ws_size;
  const float* x = (const float*)d_in[0];
  const float* WQ = (const float*)d_in[1];
  const float* WK = (const float*)d_in[2];
  const float* WV = (const float*)d_in[3];
  const float* WO = (const float*)d_in[4];

  char* ws = (char*)d_ws;
  u16* xb = (u16*)ws;            ws += (size_t)8192 * 1024 * 2;   // 16.8 MB (reused as ctx)
  u16* wcat = (u16*)ws;          ws += (size_t)3072 * 1024 * 2;   // 6.3 MB
  u16* wot = (u16*)ws;           ws += (size_t)1024 * 1024 * 2;   // 2.1 MB
  u16* qkv = (u16*)ws;           ws += (size_t)8192 * 3072 * 2;   // 50.3 MB
  u16* vt = (u16*)ws;            ws += (size_t)BB * HD * DH * SS * 2;  // 16.8 MB
  u16* ctx = xb;  // x consumed by QKV GEMM before attention writes ctx

  // 1/sqrt(1024) * log2(e): softmax runs in exp2 domain with scale folded into WQ
  const float QSCALE = 0.03125f * 1.4426950408889634f;

  cast_x_kernel<<<dim3(8192), dim3(256), 0, stream>>>(x, xb, 2097152);
  wtrans4_kernel<<<dim3(16, 16, 4), dim3(256), 0, stream>>>(WQ, WK, WV, WO, wcat, wot, QSCALE);

  gemm_nt_kernel<1><<<dim3(24, 64), dim3(256), 0, stream>>>(xb, wcat, (void*)qkv, 8192, 3072, 1024);
  vtrans_kernel<<<dim3(32, 16, 4), dim3(256), 0, stream>>>(qkv, vt);
  attn_kernel<<<dim3(8, 16, 4), dim3(256), 0, stream>>>(qkv, vt, ctx);
  gemm_nt_kernel<0><<<dim3(8, 64), dim3(256), 0, stream>>>(ctx, wot, d_out, 8192, 1024, 1024);
}